// Round 1
// baseline (915.208 us; speedup 1.0000x reference)
//
#include <hip/hip_runtime.h>
#include <stdint.h>

// CosineSimilarityCodebook: X[16384,256] f32, EMB[8192,256] f32 (gets re-l2norm'd).
// out = [quantized 16384*256 f32][indices 16384 f32-valued]
// Round 1: fp32 vector baseline (no fp32 MFMA on CDNA4). argmax is scale-invariant
// in x -> only emb rows normalized (via inv-norm applied at LDS staging time).

#define M_ROWS 16384
#define KCODES 8192
#define DDIM   256

#define BR 128          // rows per block
#define BC 128          // codes per chunk
#define DK 16           // d-slice staged in LDS
#define CSPLIT 4        // code splits across blocks (grid.y)
#define CODES_PER_SPLIT (KCODES / CSPLIT)

// order-preserving float->uint key (no NaNs in this problem)
__device__ __forceinline__ unsigned int fkey(float f) {
    unsigned int u = __float_as_uint(f);
    return (u & 0x80000000u) ? ~u : (u | 0x80000000u);
}

__device__ __forceinline__ unsigned long long shfl_xor_u64(unsigned long long v, int m) {
    unsigned int lo = (unsigned int)(v & 0xFFFFFFFFull);
    unsigned int hi = (unsigned int)(v >> 32);
    lo = __shfl_xor(lo, m, 64);
    hi = __shfl_xor(hi, m, 64);
    return ((unsigned long long)hi << 32) | (unsigned long long)lo;
}

// one wave per embedding row: inv_norm[row] = 1/max(sqrt(sum e^2), 1e-12)
__global__ void norm_emb_kernel(const float* __restrict__ emb, float* __restrict__ inv_norm) {
    int row  = blockIdx.x * 4 + (threadIdx.x >> 6);
    int lane = threadIdx.x & 63;
    float4 v = reinterpret_cast<const float4*>(emb + row * DDIM)[lane];
    float s = v.x * v.x + v.y * v.y + v.z * v.z + v.w * v.w;
    #pragma unroll
    for (int m = 32; m; m >>= 1) s += __shfl_xor(s, m, 64);
    if (lane == 0) inv_norm[row] = 1.0f / fmaxf(sqrtf(s), 1e-12f);
}

__global__ __launch_bounds__(256, 2)
void gemm_argmax_kernel(const float* __restrict__ x,
                        const float* __restrict__ emb,
                        const float* __restrict__ inv_norm,
                        unsigned long long* __restrict__ best) {
    // +4 pad keeps float4 alignment (row stride 132 floats = 528B, 16B aligned)
    // and breaks the worst write-bank collisions (132 % 32 == 4).
    __shared__ float As[DK][BR + 4];
    __shared__ float Bs[DK][BC + 4];

    const int t  = threadIdx.x;
    const int tx = t & 15;          // code sub-tile (8 codes each)
    const int ty = t >> 4;          // row sub-tile (8 rows each)
    const int rb = blockIdx.x * BR;
    const int cs = blockIdx.y * CODES_PER_SPLIT;

    unsigned long long bestr[8];
    #pragma unroll
    for (int i = 0; i < 8; ++i) bestr[i] = 0ULL;  // any real key beats 0

    for (int cb = cs; cb < cs + CODES_PER_SPLIT; cb += BC) {
        float acc[8][8];
        #pragma unroll
        for (int i = 0; i < 8; ++i)
            #pragma unroll
            for (int j = 0; j < 8; ++j) acc[i][j] = 0.0f;

        for (int db = 0; db < DDIM; db += DK) {
            __syncthreads();  // WAR: previous slice's reads done before overwrite
            #pragma unroll
            for (int p = 0; p < 2; ++p) {
                int idx = t + p * 256;
                int row = idx >> 2;            // 0..127
                int dc  = (idx & 3) * 4;       // 0,4,8,12
                float4 av = *reinterpret_cast<const float4*>(x   + (size_t)(rb + row) * DDIM + db + dc);
                float4 bv = *reinterpret_cast<const float4*>(emb + (size_t)(cb + row) * DDIM + db + dc);
                float binv = inv_norm[cb + row];
                As[dc + 0][row] = av.x; As[dc + 1][row] = av.y;
                As[dc + 2][row] = av.z; As[dc + 3][row] = av.w;
                Bs[dc + 0][row] = bv.x * binv; Bs[dc + 1][row] = bv.y * binv;
                Bs[dc + 2][row] = bv.z * binv; Bs[dc + 3][row] = bv.w * binv;
            }
            __syncthreads();

            #pragma unroll
            for (int d = 0; d < DK; ++d) {
                float4 a0 = *reinterpret_cast<const float4*>(&As[d][ty * 8]);
                float4 a1 = *reinterpret_cast<const float4*>(&As[d][ty * 8 + 4]);
                float4 b0 = *reinterpret_cast<const float4*>(&Bs[d][tx * 8]);
                float4 b1 = *reinterpret_cast<const float4*>(&Bs[d][tx * 8 + 4]);
                float ar[8] = {a0.x, a0.y, a0.z, a0.w, a1.x, a1.y, a1.z, a1.w};
                float br[8] = {b0.x, b0.y, b0.z, b0.w, b1.x, b1.y, b1.z, b1.w};
                #pragma unroll
                for (int i = 0; i < 8; ++i)
                    #pragma unroll
                    for (int j = 0; j < 8; ++j)
                        acc[i][j] = fmaf(ar[i], br[j], acc[i][j]);
            }
        }

        // fold this 128-code chunk into running per-row best
        #pragma unroll
        for (int i = 0; i < 8; ++i) {
            #pragma unroll
            for (int j = 0; j < 8; ++j) {
                unsigned int code = (unsigned int)(cb + tx * 8 + j);
                unsigned long long cand =
                    ((unsigned long long)fkey(acc[i][j]) << 32) |
                    (unsigned long long)(0xFFFFFFFFu - code);   // ties -> smaller idx wins
                if (cand > bestr[i]) bestr[i] = cand;
            }
        }
    }

    // reduce across the 16 code-columns (lane bits 0..3), ty constant per pair
    #pragma unroll
    for (int m = 1; m < 16; m <<= 1) {
        #pragma unroll
        for (int i = 0; i < 8; ++i) {
            unsigned long long o = shfl_xor_u64(bestr[i], m);
            if (o > bestr[i]) bestr[i] = o;
        }
    }
    if (tx == 0) {
        #pragma unroll
        for (int i = 0; i < 8; ++i)
            atomicMax(&best[rb + ty * 8 + i], bestr[i]);
    }
}

// one block per row: gather un-normalized embedding row + write index as float
__global__ void finalize_kernel(const unsigned long long* __restrict__ best,
                                const float* __restrict__ emb,
                                float* __restrict__ out) {
    int row = blockIdx.x;
    unsigned long long b = best[row];
    unsigned int code = 0xFFFFFFFFu - (unsigned int)(b & 0xFFFFFFFFull);
    out[(size_t)row * DDIM + threadIdx.x] = emb[(size_t)code * DDIM + threadIdx.x];
    if (threadIdx.x == 0) out[(size_t)M_ROWS * DDIM + row] = (float)code;
}

extern "C" void kernel_launch(void* const* d_in, const int* in_sizes, int n_in,
                              void* d_out, int out_size, void* d_ws, size_t ws_size,
                              hipStream_t stream) {
    const float* x   = (const float*)d_in[0];   // 4*4096*256
    const float* emb = (const float*)d_in[1];   // 8192*256
    float* out = (float*)d_out;

    // ws: [inv_norm f32 x 8192][best u64 x 16384]  (= 160 KB)
    float* inv_norm = (float*)d_ws;
    unsigned long long* best =
        (unsigned long long*)((char*)d_ws + KCODES * sizeof(float));

    hipMemsetAsync(best, 0, M_ROWS * sizeof(unsigned long long), stream);
    norm_emb_kernel<<<KCODES / 4, 256, 0, stream>>>(emb, inv_norm);
    gemm_argmax_kernel<<<dim3(M_ROWS / BR, CSPLIT), 256, 0, stream>>>(x, emb, inv_norm, best);
    finalize_kernel<<<M_ROWS, 256, 0, stream>>>(best, emb, out);
}

// Round 4
// 473.717 us; speedup vs baseline: 1.9320x; 1.9320x over previous
//
#include <hip/hip_runtime.h>
#include <stdint.h>

// CosineSimilarityCodebook: X[16384,256] f32, EMB[8192,256] f32 (re-l2norm'd).
// out = [quantized 16384*256 f32][indices 16384 as f32]
// R2 (2nd resubmit after broker timeouts): split-f16 MFMA.
// dist = hi_x*hi_e + (hi_x*lo_e' + lo_x'*hi_e)/512,
// lo' = (v - (f32)hi)*512 (scaled past the f16-denormal flush zone).
// Omitted lo*lo term ~6e-8 << min top1/top2 gap (~1e-5, bounded by R1 absmax=0).

#define M_ROWS 16384
#define KCODES 8192
#define DDIM   256

#define BR   128      // rows per block
#define BCC  128      // codes per chunk (acc width)
#define BK   32       // K-slice in LDS
#define NSPLIT 8      // code splits (grid.y)
#define CPS  (KCODES / NSPLIT)   // 1024 codes per block
#define LSCALE     512.0f
#define INV_LSCALE (1.0f / 512.0f)
#define LDP  (BK + 8) // padded LDS row: 40 halves = 80B -> 20-bank step, 2-way max

typedef _Float16 half4v __attribute__((ext_vector_type(4)));
typedef _Float16 half8v __attribute__((ext_vector_type(8)));
typedef float    f32x4  __attribute__((ext_vector_type(4)));

// order-preserving float->uint key (no NaNs here)
__device__ __forceinline__ unsigned int fkey(float f) {
    unsigned int u = __float_as_uint(f);
    return (u & 0x80000000u) ? ~u : (u | 0x80000000u);
}

// one wave per embedding row: inv_norm[row] = 1/max(sqrt(sum e^2), 1e-12)
__global__ void norm_emb_kernel(const float* __restrict__ emb, float* __restrict__ inv_norm) {
    int row  = blockIdx.x * 4 + (threadIdx.x >> 6);
    int lane = threadIdx.x & 63;
    float4 v = reinterpret_cast<const float4*>(emb + row * DDIM)[lane];
    float s = v.x * v.x + v.y * v.y + v.z * v.z + v.w * v.w;
    #pragma unroll
    for (int m = 32; m; m >>= 1) s += __shfl_xor(s, m, 64);
    if (lane == 0) inv_norm[row] = 1.0f / fmaxf(sqrtf(s), 1e-12f);
}

__device__ __forceinline__ void split4(float a, float b, float c, float d,
                                       half4v& h, half4v& lo) {
    h[0] = (_Float16)a; lo[0] = (_Float16)((a - (float)h[0]) * LSCALE);
    h[1] = (_Float16)b; lo[1] = (_Float16)((b - (float)h[1]) * LSCALE);
    h[2] = (_Float16)c; lo[2] = (_Float16)((c - (float)h[2]) * LSCALE);
    h[3] = (_Float16)d; lo[3] = (_Float16)((d - (float)h[3]) * LSCALE);
}

__global__ __launch_bounds__(256, 2)
void mfma_argmax_kernel(const float* __restrict__ x,
                        const float* __restrict__ emb,
                        const float* __restrict__ invn,
                        unsigned long long* __restrict__ best) {
    __shared__ _Float16 Ah[BR][LDP];
    __shared__ _Float16 Al[BR][LDP];
    __shared__ _Float16 Bh[BCC][LDP];
    __shared__ _Float16 Bl[BCC][LDP];

    const int t   = threadIdx.x;
    const int l   = t & 63;
    const int wid = t >> 6;
    const int wy  = wid >> 1, wx = wid & 1;   // 2x2 wave grid, 64x64 each
    const int rb  = blockIdx.x * BR;
    const int cs  = blockIdx.y * CPS;
    const int lr  = l & 15;
    const int lk  = (l >> 4) * 8;             // K-offset of this lane's fragment

    const int srow = t >> 3;                  // staging: 8 threads per row
    const int sc4  = (t & 7) * 4;             // each thread one float4 of the 32-col slice

    float bestv[16];
    unsigned int bestc[16];
    #pragma unroll
    for (int i = 0; i < 16; ++i) { bestv[i] = -1e30f; bestc[i] = 0; }

    #pragma unroll 1
    for (int cc = 0; cc < CPS; cc += BCC) {
        const int cb = cs + cc;
        float bn[4];
        #pragma unroll
        for (int it = 0; it < 4; ++it) bn[it] = invn[cb + srow + it * 32];

        f32x4 acc[4][4];    // hi*hi
        f32x4 acc2[4][4];   // (hi*lo' + lo'*hi), scaled by 512
        #pragma unroll
        for (int m = 0; m < 4; ++m)
            #pragma unroll
            for (int n = 0; n < 4; ++n) {
                acc[m][n]  = (f32x4){0.f, 0.f, 0.f, 0.f};
                acc2[m][n] = (f32x4){0.f, 0.f, 0.f, 0.f};
            }

        #pragma unroll 1
        for (int db = 0; db < DDIM; db += BK) {
            __syncthreads();   // WAR: previous slice's reads done
            #pragma unroll
            for (int it = 0; it < 4; ++it) {
                int row = srow + it * 32;
                float4 av = *reinterpret_cast<const float4*>(
                    x + (size_t)(rb + row) * DDIM + db + sc4);
                half4v h, lo;
                split4(av.x, av.y, av.z, av.w, h, lo);
                *reinterpret_cast<half4v*>(&Ah[row][sc4]) = h;
                *reinterpret_cast<half4v*>(&Al[row][sc4]) = lo;

                float4 bv = *reinterpret_cast<const float4*>(
                    emb + (size_t)(cb + row) * DDIM + db + sc4);
                float s = bn[it];
                split4(bv.x * s, bv.y * s, bv.z * s, bv.w * s, h, lo);
                *reinterpret_cast<half4v*>(&Bh[row][sc4]) = h;
                *reinterpret_cast<half4v*>(&Bl[row][sc4]) = lo;
            }
            __syncthreads();

            half8v ah[4], al[4];
            #pragma unroll
            for (int m = 0; m < 4; ++m) {
                ah[m] = *reinterpret_cast<const half8v*>(&Ah[wy * 64 + m * 16 + lr][lk]);
                al[m] = *reinterpret_cast<const half8v*>(&Al[wy * 64 + m * 16 + lr][lk]);
            }
            #pragma unroll
            for (int n = 0; n < 4; ++n) {
                half8v bh = *reinterpret_cast<const half8v*>(&Bh[wx * 64 + n * 16 + lr][lk]);
                half8v bl = *reinterpret_cast<const half8v*>(&Bl[wx * 64 + n * 16 + lr][lk]);
                #pragma unroll
                for (int m = 0; m < 4; ++m) {
                    acc[m][n]  = __builtin_amdgcn_mfma_f32_16x16x32_f16(ah[m], bh, acc[m][n],  0, 0, 0);
                    acc2[m][n] = __builtin_amdgcn_mfma_f32_16x16x32_f16(ah[m], bl, acc2[m][n], 0, 0, 0);
                    acc2[m][n] = __builtin_amdgcn_mfma_f32_16x16x32_f16(al[m], bh, acc2[m][n], 0, 0, 0);
                }
            }
        }

        // fold chunk into running per-row best (C layout: col=lane&15, row=(lane>>4)*4+reg)
        #pragma unroll
        for (int m = 0; m < 4; ++m)
            #pragma unroll
            for (int r = 0; r < 4; ++r) {
                int bi = m * 4 + r;
                #pragma unroll
                for (int n = 0; n < 4; ++n) {
                    float v = acc[m][n][r] + acc2[m][n][r] * INV_LSCALE;
                    unsigned int code = cb + wx * 64 + n * 16 + lr;
                    if (v > bestv[bi]) { bestv[bi] = v; bestc[bi] = code; }
                }
            }
    }

    // reduce across the 16 columns (lane bits 0..3); ties -> smaller code
    #pragma unroll
    for (int mb = 1; mb < 16; mb <<= 1) {
        #pragma unroll
        for (int i = 0; i < 16; ++i) {
            float ov        = __shfl_xor(bestv[i], mb, 64);
            unsigned int oc = __shfl_xor(bestc[i], mb, 64);
            if (ov > bestv[i] || (ov == bestv[i] && oc < bestc[i])) {
                bestv[i] = ov; bestc[i] = oc;
            }
        }
    }
    if (lr == 0) {
        #pragma unroll
        for (int m = 0; m < 4; ++m)
            #pragma unroll
            for (int r = 0; r < 4; ++r) {
                int row_global = rb + wy * 64 + m * 16 + (l >> 4) * 4 + r;
                int bi = m * 4 + r;
                unsigned long long key =
                    ((unsigned long long)fkey(bestv[bi]) << 32) |
                    (unsigned long long)(0xFFFFFFFFu - bestc[bi]);
                atomicMax(&best[row_global], key);
            }
    }
}

// one block per row: gather un-normalized embedding row + write index as float
__global__ void finalize_kernel(const unsigned long long* __restrict__ best,
                                const float* __restrict__ emb,
                                float* __restrict__ out) {
    int row = blockIdx.x;
    unsigned long long b = best[row];
    unsigned int code = 0xFFFFFFFFu - (unsigned int)(b & 0xFFFFFFFFull);
    out[(size_t)row * DDIM + threadIdx.x] = emb[(size_t)code * DDIM + threadIdx.x];
    if (threadIdx.x == 0) out[(size_t)M_ROWS * DDIM + row] = (float)code;
}

extern "C" void kernel_launch(void* const* d_in, const int* in_sizes, int n_in,
                              void* d_out, int out_size, void* d_ws, size_t ws_size,
                              hipStream_t stream) {
    const float* x   = (const float*)d_in[0];   // 4*4096*256
    const float* emb = (const float*)d_in[1];   // 8192*256
    float* out = (float*)d_out;

    // ws: [inv_norm f32 x 8192][best u64 x 16384]
    float* inv_norm = (float*)d_ws;
    unsigned long long* best =
        (unsigned long long*)((char*)d_ws + KCODES * sizeof(float));

    hipMemsetAsync(best, 0, M_ROWS * sizeof(unsigned long long), stream);
    norm_emb_kernel<<<KCODES / 4, 256, 0, stream>>>(emb, inv_norm);
    mfma_argmax_kernel<<<dim3(M_ROWS / BR, NSPLIT), 256, 0, stream>>>(x, emb, inv_norm, best);
    finalize_kernel<<<M_ROWS, 256, 0, stream>>>(best, emb, out);
}

// Round 5
// 289.943 us; speedup vs baseline: 3.1565x; 1.6338x over previous
//
#include <hip/hip_runtime.h>
#include <stdint.h>

// CosineSimilarityCodebook: X[16384,256] f32, EMB[8192,256] f32 (re-l2norm'd).
// out = [quantized 16384*256 f32][indices 16384 as f32]
// R5: precomputed f16 hi/lo split arrays + global_load_lds(16B) staging with
// both-sides XOR swizzle + double-buffered 2-phase K-loop.
// Math identical to R4 (absmax 0.0): dist = hh + (h*lo' + lo'*h)/512.

#define M_ROWS 16384
#define KCODES 8192
#define DDIM   256

#define BR   128
#define BCC  128
#define BK   32
#define NSPLIT 8
#define CPS  (KCODES / NSPLIT)          // 1024
#define NSLICE ((CPS / BCC) * (DDIM / BK))  // 8 chunks * 8 k-steps = 64
#define LSCALE     512.0f
#define INV_LSCALE (1.0f / 512.0f)
#define TILE_H 4096                      // halves per tile: 128 rows * 32

typedef _Float16 half8v __attribute__((ext_vector_type(8)));
typedef float    f32x4  __attribute__((ext_vector_type(4)));

__device__ __forceinline__ unsigned int fkey(float f) {
    unsigned int u = __float_as_uint(f);
    return (u & 0x80000000u) ? ~u : (u | 0x80000000u);
}

__device__ __forceinline__ void gload16(const void* g, void* l) {
    __builtin_amdgcn_global_load_lds(
        (const __attribute__((address_space(1))) void*)g,
        (__attribute__((address_space(3))) void*)l, 16, 0, 0);
}

// ---------- precompute ----------

__global__ void norm_emb_kernel(const float* __restrict__ emb, float* __restrict__ inv_norm) {
    int row  = blockIdx.x * 4 + (threadIdx.x >> 6);
    int lane = threadIdx.x & 63;
    float4 v = reinterpret_cast<const float4*>(emb + row * DDIM)[lane];
    float s = v.x * v.x + v.y * v.y + v.z * v.z + v.w * v.w;
    #pragma unroll
    for (int m = 32; m; m >>= 1) s += __shfl_xor(s, m, 64);
    if (lane == 0) inv_norm[row] = 1.0f / fmaxf(sqrtf(s), 1e-12f);
}

// 8 floats/thread -> xh/xl (f16 hi + scaled residual)
__global__ void split_x_kernel(const float* __restrict__ x,
                               _Float16* __restrict__ xh, _Float16* __restrict__ xl) {
    int i = (blockIdx.x * 256 + threadIdx.x) * 8;
    float4 v0 = *reinterpret_cast<const float4*>(x + i);
    float4 v1 = *reinterpret_cast<const float4*>(x + i + 4);
    float v[8] = {v0.x, v0.y, v0.z, v0.w, v1.x, v1.y, v1.z, v1.w};
    half8v h, lo;
    #pragma unroll
    for (int j = 0; j < 8; ++j) {
        _Float16 hh = (_Float16)v[j];
        h[j]  = hh;
        lo[j] = (_Float16)((v[j] - (float)hh) * LSCALE);
    }
    *reinterpret_cast<half8v*>(xh + i) = h;
    *reinterpret_cast<half8v*>(xl + i) = lo;
}

__global__ void split_e_kernel(const float* __restrict__ emb, const float* __restrict__ invn,
                               _Float16* __restrict__ eh, _Float16* __restrict__ el) {
    int i = (blockIdx.x * 256 + threadIdx.x) * 8;
    float s = invn[i >> 8];
    float4 v0 = *reinterpret_cast<const float4*>(emb + i);
    float4 v1 = *reinterpret_cast<const float4*>(emb + i + 4);
    float v[8] = {v0.x * s, v0.y * s, v0.z * s, v0.w * s,
                  v1.x * s, v1.y * s, v1.z * s, v1.w * s};
    half8v h, lo;
    #pragma unroll
    for (int j = 0; j < 8; ++j) {
        _Float16 hh = (_Float16)v[j];
        h[j]  = hh;
        lo[j] = (_Float16)((v[j] - (float)hh) * LSCALE);
    }
    *reinterpret_cast<half8v*>(eh + i) = h;
    *reinterpret_cast<half8v*>(el + i) = lo;
}

// ---------- main: 3-term f16 MFMA GEMM-argmax ----------
// LDS tile [128 rows][32 halves] (64B rows), 16B-slot swizzle:
//   byte(row, kg) = row*64 + (kg ^ ((row>>1)&3))*16
// gload_lds writes linearly -> global source pre-swizzled per-lane:
//   lane i: row=i>>2, slot=i&3, fetches logical kg = (i&3)^((i>>3)&3).

__global__ __launch_bounds__(256, 2)
void mfma3_kernel(const _Float16* __restrict__ xh, const _Float16* __restrict__ xl,
                  const _Float16* __restrict__ eh, const _Float16* __restrict__ el,
                  unsigned long long* __restrict__ best) {
    __shared__ _Float16 lds[2][4 * TILE_H];   // 2 bufs * 4 tiles * 8KB = 64KB

    const int t  = threadIdx.x;
    const int l  = t & 63;
    const int w  = t >> 6;                 // wave id; wave w stages tile w
    const int wy = w >> 1, wx = w & 1;     // 2x2 wave grid, 64x64 each
    const int rb = blockIdx.x * BR;
    const int cs = blockIdx.y * CPS;
    const int lr = l & 15;
    const int kg = l >> 4;

    // staging lane decomposition (within a 1KB chunk = 16 rows x 4 slots)
    const int s_row = l >> 2;
    const int s_kg  = (l & 3) ^ ((l >> 3) & 3);

    // ds_read swizzled per-lane offset (halves): row*32 + slot*8
    const int rd_off = lr * 32 + (kg ^ ((lr >> 1) & 3)) * 8;
    const int a_base = wy * 64 * 32 + rd_off;     // + m*16*32
    const int b_base = wx * 64 * 32 + rd_off;     // + n*16*32

    const _Float16* gsrc = (w == 0) ? xh : (w == 1) ? xl : (w == 2) ? eh : el;
    const int g_is_x = (w < 2);

    float bestv[16];
    unsigned int bestc[16];
    #pragma unroll
    for (int i = 0; i < 16; ++i) { bestv[i] = -1e30f; bestc[i] = 0; }

    f32x4 acc[4][4];    // hi*hi
    f32x4 acc2[4][4];   // cross terms (scaled by 512)

    // stage slice 0
    {
        const _Float16* gp = gsrc + (g_is_x ? rb : cs) * DDIM + s_row * DDIM + s_kg * 8;
        _Float16* lp = &lds[0][w * TILE_H];
        #pragma unroll
        for (int c = 0; c < 8; ++c)
            gload16(gp + c * 16 * DDIM, lp + c * 512);
    }
    __syncthreads();   // drains vmcnt(0) too

    int buf = 0;
    #pragma unroll 1
    for (int st = 0; st < NSLICE; ++st) {
        const int cb = cs + (st >> 3) * BCC;

        if ((st & 7) == 0) {
            #pragma unroll
            for (int m = 0; m < 4; ++m)
                #pragma unroll
                for (int n = 0; n < 4; ++n) {
                    acc[m][n]  = (f32x4){0.f, 0.f, 0.f, 0.f};
                    acc2[m][n] = (f32x4){0.f, 0.f, 0.f, 0.f};
                }
        }

        // issue next slice's staging into the other buffer
        if (st + 1 < NSLICE) {
            const int ncb = cs + ((st + 1) >> 3) * BCC;
            const int ndb = ((st + 1) & 7) * BK;
            const _Float16* gp = gsrc + (g_is_x ? rb : ncb) * DDIM + ndb
                                 + s_row * DDIM + s_kg * 8;
            _Float16* lp = &lds[buf ^ 1][w * TILE_H];
            #pragma unroll
            for (int c = 0; c < 8; ++c)
                gload16(gp + c * 16 * DDIM, lp + c * 512);
        }

        // compute current slice
        const _Float16* L = lds[buf];
        half8v ah[4], al[4];
        #pragma unroll
        for (int m = 0; m < 4; ++m) {
            ah[m] = *reinterpret_cast<const half8v*>(&L[0 * TILE_H + a_base + m * 512]);
            al[m] = *reinterpret_cast<const half8v*>(&L[1 * TILE_H + a_base + m * 512]);
        }
        #pragma unroll
        for (int n = 0; n < 4; ++n) {
            half8v bh = *reinterpret_cast<const half8v*>(&L[2 * TILE_H + b_base + n * 512]);
            half8v bl = *reinterpret_cast<const half8v*>(&L[3 * TILE_H + b_base + n * 512]);
            #pragma unroll
            for (int m = 0; m < 4; ++m) {
                acc[m][n]  = __builtin_amdgcn_mfma_f32_16x16x32_f16(ah[m], bh, acc[m][n],  0, 0, 0);
                acc2[m][n] = __builtin_amdgcn_mfma_f32_16x16x32_f16(ah[m], bl, acc2[m][n], 0, 0, 0);
                acc2[m][n] = __builtin_amdgcn_mfma_f32_16x16x32_f16(al[m], bh, acc2[m][n], 0, 0, 0);
            }
        }

        // fold at chunk end (register-only; overlaps in-flight staging)
        if ((st & 7) == 7) {
            #pragma unroll
            for (int m = 0; m < 4; ++m)
                #pragma unroll
                for (int r = 0; r < 4; ++r) {
                    int bi = m * 4 + r;
                    #pragma unroll
                    for (int n = 0; n < 4; ++n) {
                        float v = acc[m][n][r] + acc2[m][n][r] * INV_LSCALE;
                        unsigned int code = cb + wx * 64 + n * 16 + lr;
                        if (v > bestv[bi]) { bestv[bi] = v; bestc[bi] = code; }
                    }
                }
        }

        __syncthreads();   // waits vmcnt(0) (next-slice staging) + lds reads done
        buf ^= 1;
    }

    // reduce across the 16 code-columns (lane bits 0..3); ties -> smaller code
    #pragma unroll
    for (int mb = 1; mb < 16; mb <<= 1) {
        #pragma unroll
        for (int i = 0; i < 16; ++i) {
            float ov        = __shfl_xor(bestv[i], mb, 64);
            unsigned int oc = __shfl_xor(bestc[i], mb, 64);
            if (ov > bestv[i] || (ov == bestv[i] && oc < bestc[i])) {
                bestv[i] = ov; bestc[i] = oc;
            }
        }
    }
    if (lr == 0) {
        #pragma unroll
        for (int m = 0; m < 4; ++m)
            #pragma unroll
            for (int r = 0; r < 4; ++r) {
                int row_global = rb + wy * 64 + m * 16 + (l >> 4) * 4 + r;
                int bi = m * 4 + r;
                unsigned long long key =
                    ((unsigned long long)fkey(bestv[bi]) << 32) |
                    (unsigned long long)(0xFFFFFFFFu - bestc[bi]);
                atomicMax(&best[row_global], key);
            }
    }
}

// ---------- fallback (R4, proven): in-loop split staging ----------
#define LDP  (BK + 8)

typedef _Float16 half4v __attribute__((ext_vector_type(4)));

__device__ __forceinline__ void split4(float a, float b, float c, float d,
                                       half4v& h, half4v& lo) {
    h[0] = (_Float16)a; lo[0] = (_Float16)((a - (float)h[0]) * LSCALE);
    h[1] = (_Float16)b; lo[1] = (_Float16)((b - (float)h[1]) * LSCALE);
    h[2] = (_Float16)c; lo[2] = (_Float16)((c - (float)h[2]) * LSCALE);
    h[3] = (_Float16)d; lo[3] = (_Float16)((d - (float)h[3]) * LSCALE);
}

__global__ __launch_bounds__(256, 2)
void mfma_argmax_fb(const float* __restrict__ x, const float* __restrict__ emb,
                    const float* __restrict__ invn, unsigned long long* __restrict__ best) {
    __shared__ _Float16 Ah[BR][LDP];
    __shared__ _Float16 Al[BR][LDP];
    __shared__ _Float16 Bh[BCC][LDP];
    __shared__ _Float16 Bl[BCC][LDP];
    const int t = threadIdx.x, l = t & 63, wid = t >> 6;
    const int wy = wid >> 1, wx = wid & 1;
    const int rb = blockIdx.x * BR, cs = blockIdx.y * CPS;
    const int lr = l & 15, lk = (l >> 4) * 8;
    const int srow = t >> 3, sc4 = (t & 7) * 4;
    float bestv[16]; unsigned int bestc[16];
    #pragma unroll
    for (int i = 0; i < 16; ++i) { bestv[i] = -1e30f; bestc[i] = 0; }
    #pragma unroll 1
    for (int cc = 0; cc < CPS; cc += BCC) {
        const int cb = cs + cc;
        float bn[4];
        #pragma unroll
        for (int it = 0; it < 4; ++it) bn[it] = invn[cb + srow + it * 32];
        f32x4 acc[4][4], acc2[4][4];
        #pragma unroll
        for (int m = 0; m < 4; ++m)
            #pragma unroll
            for (int n = 0; n < 4; ++n) {
                acc[m][n] = (f32x4){0.f,0.f,0.f,0.f}; acc2[m][n] = (f32x4){0.f,0.f,0.f,0.f};
            }
        #pragma unroll 1
        for (int db = 0; db < DDIM; db += BK) {
            __syncthreads();
            #pragma unroll
            for (int it = 0; it < 4; ++it) {
                int row = srow + it * 32;
                float4 av = *reinterpret_cast<const float4*>(x + (size_t)(rb + row) * DDIM + db + sc4);
                half4v h, lo;
                split4(av.x, av.y, av.z, av.w, h, lo);
                *reinterpret_cast<half4v*>(&Ah[row][sc4]) = h;
                *reinterpret_cast<half4v*>(&Al[row][sc4]) = lo;
                float4 bv = *reinterpret_cast<const float4*>(emb + (size_t)(cb + row) * DDIM + db + sc4);
                float s = bn[it];
                split4(bv.x * s, bv.y * s, bv.z * s, bv.w * s, h, lo);
                *reinterpret_cast<half4v*>(&Bh[row][sc4]) = h;
                *reinterpret_cast<half4v*>(&Bl[row][sc4]) = lo;
            }
            __syncthreads();
            half8v ah[4], al[4];
            #pragma unroll
            for (int m = 0; m < 4; ++m) {
                ah[m] = *reinterpret_cast<const half8v*>(&Ah[wy * 64 + m * 16 + lr][lk]);
                al[m] = *reinterpret_cast<const half8v*>(&Al[wy * 64 + m * 16 + lr][lk]);
            }
            #pragma unroll
            for (int n = 0; n < 4; ++n) {
                half8v bh = *reinterpret_cast<const half8v*>(&Bh[wx * 64 + n * 16 + lr][lk]);
                half8v bl = *reinterpret_cast<const half8v*>(&Bl[wx * 64 + n * 16 + lr][lk]);
                #pragma unroll
                for (int m = 0; m < 4; ++m) {
                    acc[m][n]  = __builtin_amdgcn_mfma_f32_16x16x32_f16(ah[m], bh, acc[m][n],  0, 0, 0);
                    acc2[m][n] = __builtin_amdgcn_mfma_f32_16x16x32_f16(ah[m], bl, acc2[m][n], 0, 0, 0);
                    acc2[m][n] = __builtin_amdgcn_mfma_f32_16x16x32_f16(al[m], bh, acc2[m][n], 0, 0, 0);
                }
            }
        }
        #pragma unroll
        for (int m = 0; m < 4; ++m)
            #pragma unroll
            for (int r = 0; r < 4; ++r) {
                int bi = m * 4 + r;
                #pragma unroll
                for (int n = 0; n < 4; ++n) {
                    float v = acc[m][n][r] + acc2[m][n][r] * INV_LSCALE;
                    unsigned int code = cb + wx * 64 + n * 16 + lr;
                    if (v > bestv[bi]) { bestv[bi] = v; bestc[bi] = code; }
                }
            }
    }
    #pragma unroll
    for (int mb = 1; mb < 16; mb <<= 1) {
        #pragma unroll
        for (int i = 0; i < 16; ++i) {
            float ov = __shfl_xor(bestv[i], mb, 64);
            unsigned int oc = __shfl_xor(bestc[i], mb, 64);
            if (ov > bestv[i] || (ov == bestv[i] && oc < bestc[i])) { bestv[i] = ov; bestc[i] = oc; }
        }
    }
    if (lr == 0) {
        #pragma unroll
        for (int m = 0; m < 4; ++m)
            #pragma unroll
            for (int r = 0; r < 4; ++r) {
                int row_global = rb + wy * 64 + m * 16 + (l >> 4) * 4 + r;
                int bi = m * 4 + r;
                unsigned long long key = ((unsigned long long)fkey(bestv[bi]) << 32) |
                                         (unsigned long long)(0xFFFFFFFFu - bestc[bi]);
                atomicMax(&best[row_global], key);
            }
    }
}

// one block per row: gather un-normalized embedding row + write index as float
__global__ void finalize_kernel(const unsigned long long* __restrict__ best,
                                const float* __restrict__ emb,
                                float* __restrict__ out) {
    int row = blockIdx.x;
    unsigned long long b = best[row];
    unsigned int code = 0xFFFFFFFFu - (unsigned int)(b & 0xFFFFFFFFull);
    out[(size_t)row * DDIM + threadIdx.x] = emb[(size_t)code * DDIM + threadIdx.x];
    if (threadIdx.x == 0) out[(size_t)M_ROWS * DDIM + row] = (float)code;
}

extern "C" void kernel_launch(void* const* d_in, const int* in_sizes, int n_in,
                              void* d_out, int out_size, void* d_ws, size_t ws_size,
                              hipStream_t stream) {
    const float* x   = (const float*)d_in[0];
    const float* emb = (const float*)d_in[1];
    float* out = (float*)d_out;

    // ws: [best u64 x 16384 = 128KB][inv_norm 32KB][xh 8MB][xl 8MB][eh 4MB][el 4MB]
    unsigned long long* best = (unsigned long long*)d_ws;
    float* inv_norm = (float*)((char*)d_ws + 128 * 1024);
    const size_t split_off = 160 * 1024;
    const size_t need = split_off +
                        (size_t)M_ROWS * DDIM * 2 * sizeof(_Float16) +
                        (size_t)KCODES * DDIM * 2 * sizeof(_Float16);

    hipMemsetAsync(best, 0, M_ROWS * sizeof(unsigned long long), stream);
    norm_emb_kernel<<<KCODES / 4, 256, 0, stream>>>(emb, inv_norm);

    if (ws_size >= need) {
        _Float16* xh = (_Float16*)((char*)d_ws + split_off);
        _Float16* xl = xh + (size_t)M_ROWS * DDIM;
        _Float16* eh = xl + (size_t)M_ROWS * DDIM;
        _Float16* el = eh + (size_t)KCODES * DDIM;
        split_x_kernel<<<M_ROWS * DDIM / (256 * 8), 256, 0, stream>>>(x, xh, xl);
        split_e_kernel<<<KCODES * DDIM / (256 * 8), 256, 0, stream>>>(emb, inv_norm, eh, el);
        mfma3_kernel<<<dim3(M_ROWS / BR, NSPLIT), 256, 0, stream>>>(xh, xl, eh, el, best);
    } else {
        mfma_argmax_fb<<<dim3(M_ROWS / BR, NSPLIT), 256, 0, stream>>>(x, emb, inv_norm, best);
    }
    finalize_kernel<<<M_ROWS, 256, 0, stream>>>(best, emb, out);
}